// Round 16
// baseline (453.190 us; speedup 1.0000x reference)
//
#include <hip/hip_runtime.h>

#define N_NODES 100000
#define N_EDGES 3200000
#define N_GRAPHS 2048
#define VOCAB 92
#define H 64
#define N_LAYERS 3

#define BUCK_BITS 6
#define BUCK_NODES (1 << BUCK_BITS)                          // 64 nodes / bucket
#define NBUCK ((N_NODES + BUCK_NODES - 1) / BUCK_NODES)      // 1563

#define PART_BLOCKS 256                                      // == k_bg blockDim!
#define EDGES_PER_PART (N_EDGES / PART_BLOCKS)               // 12500
#define BS_STRIDE (NBUCK + 1)                                // blkstart row stride

#define BIN_CAP 2560       // LDS slice cap: bucket load ~Poisson(2048), max≈2256

// layer-0 MFMA geometry (tile == bucket == 64 nodes)
#define G0_TILE 64
#define SBINS_STRIDE 100   // f32 bins stride (92 used, pad to break banks)
#define SB_STRIDE 104      // f16 tile stride (92->96 K-pad, +8 bank pad)

// fused layer kernel geometry
#define FL_TILE 64
#define A_STRIDE 72        // f16 LDS stride (64 + 8 pad -> 2-way banks, free)

typedef _Float16 half8 __attribute__((ext_vector_type(8)));
typedef _Float16 half2t __attribute__((ext_vector_type(2)));
typedef float f32x4 __attribute__((ext_vector_type(4)));

// fp32 -> bf16 (round-to-nearest-even)
__device__ inline unsigned short f2bf(float f) {
    union { float f; unsigned u; } v; v.f = f;
    unsigned u = v.u;
    u += 0x7fffu + ((u >> 16) & 1u);
    return (unsigned short)(u >> 16);
}
__device__ inline float bfhi(unsigned p) {
    union { unsigned u; float f; } v; v.u = p & 0xffff0000u; return v.f;
}
__device__ inline float bflo(unsigned p) {
    union { unsigned u; float f; } v; v.u = p << 16; return v.f;
}
__device__ inline float bf2f(unsigned short b) {
    union { unsigned u; float f; } v; v.u = ((unsigned)b) << 16; return v.f;
}

// ---- OFFSET-BINADE fp8 (bias 7): code = e4m3(v + 2^-6), v >= 0.
// All codes NORMAL; f16 decode (em<<7)+0x2000 == f32 decode exactly.
// PACKED decode: 2 codes -> half2 in 3 int ops; accumulate v_pk_add_f16.
// Offset removed exactly post-reduce (masked tail lanes inject code 8).

__device__ inline unsigned char fp8e(float v) {   // v >= 0, v < ~200
    union { float f; unsigned u; } a; a.f = v + 0.015625f;
    unsigned u = a.u + 0x0007FFFFu + ((a.u >> 20) & 1u);   // RNE into bit 20
    return (unsigned char)((u >> 20) - 960u);               // (e-120)<<3 | m3
}

__device__ inline half2t ph(unsigned u) {
    union { unsigned u; half2t h; } t; t.u = u; return t.h;
}
__device__ inline unsigned hu(half2t h) {
    union { half2t h; unsigned u; } t; t.h = h; return t.u;
}

// decode+accumulate 8 offset-fp8 codes (uint2):
//   a[0]+=(ch0,ch2) a[1]+=(ch1,ch3) a[2]+=(ch4,ch6) a[3]+=(ch5,ch7)
__device__ inline void unpack_add8(uint2 v, half2t* a) {
    a[0] += ph(((v.x & 0x00FF00FFu) << 7) + 0x20002000u);
    a[1] += ph(((v.x >> 1) & 0x7F807F80u) + 0x20002000u);
    a[2] += ph(((v.y & 0x00FF00FFu) << 7) + 0x20002000u);
    a[3] += ph(((v.y >> 1) & 0x7F807F80u) + 0x20002000u);
}

// ---------------- kernels ----------------

// merged: M = emb @ W0 (one block per vocab row) + zero bcnt/srpad/degi.
__global__ void k_pre(const float* __restrict__ emb, const float* __restrict__ W0,
                      float* __restrict__ M, int* __restrict__ bcnt,
                      int* __restrict__ srpad, int* __restrict__ degi) {
    int v = blockIdx.x, c = threadIdx.x;
    int i = v * 64 + c;   // 0..5887
    if (i < NBUCK) bcnt[i] = 0;
    if (v == 0 && c < 64) srpad[c] = 0;
    for (int t = i; t < N_NODES; t += VOCAB * 64) degi[t] = 0;
    float acc = 0.0f;
#pragma unroll
    for (int k = 0; k < H; ++k) acc += emb[v * H + k] * W0[k * H + c];
    M[v * H + c] = acc;
}

// binA (block-major): counting-sort own chunk by bucket into own staging
// region (one writer/XCD per line). ALSO: global node-degree atomics (breaks
// the packed[] dependency cycle so binB+gather0 can merge), blkstart, bcnt.
__global__ __launch_bounds__(1024) void k_binA(const int* __restrict__ row,
                                               const int* __restrict__ col,
                                               int* __restrict__ bcnt,
                                               int* __restrict__ blkstart,
                                               int* __restrict__ staging,
                                               int* __restrict__ degi) {
    __shared__ int lh[NBUCK];    // histogram, then rank counters
    __shared__ int lsc[NBUCK];   // exclusive scan (chunk-local offsets)
    __shared__ int s[2048];      // scan workspace
    int tid = threadIdx.x;
    int base = blockIdx.x * EDGES_PER_PART;

    for (int i = tid; i < NBUCK; i += 1024) lh[i] = 0;
    __syncthreads();
    for (int k = tid; k < EDGES_PER_PART; k += 1024) {
        int c = col[base + k];
        atomicAdd(&lh[c >> BUCK_BITS], 1);
        atomicAdd(&degi[c], 1);   // fire-and-forget, L2-resident 400KB table
    }
    __syncthreads();

    int p0 = tid, p1 = tid + 1024;
    int v0 = (p0 < NBUCK) ? lh[p0] : 0;
    int v1 = (p1 < NBUCK) ? lh[p1] : 0;
    s[p0] = v0; s[p1] = v1;
    __syncthreads();
    for (int off = 1; off < 2048; off <<= 1) {
        int t0 = (p0 >= off) ? s[p0 - off] : 0;
        int t1 = (p1 >= off) ? s[p1 - off] : 0;
        __syncthreads();
        s[p0] += t0; s[p1] += t1;
        __syncthreads();
    }
    int* myrow = blkstart + (size_t)blockIdx.x * BS_STRIDE;
    if (p0 < NBUCK) {
        int e = s[p0] - v0;
        lsc[p0] = e;
        myrow[p0] = base + e;
        if (v0) atomicAdd(&bcnt[p0], v0);
        lh[p0] = 0;
    }
    if (p1 < NBUCK) {
        int e = s[p1] - v1;
        lsc[p1] = e;
        myrow[p1] = base + e;
        if (v1) atomicAdd(&bcnt[p1], v1);
        lh[p1] = 0;
    }
    if (tid == 0) myrow[NBUCK] = base + EDGES_PER_PART;
    __syncthreads();

    for (int k = tid; k < EDGES_PER_PART; k += 1024) {
        int c = col[base + k];
        int b = c >> BUCK_BITS;
        int r = atomicAdd(&lh[b], 1);
        staging[base + lsc[b] + r] = row[base + k] | ((c & (BUCK_NODES - 1)) << 17);
    }
}

// node metadata from global degrees: dinv + packed(x, dinv_bf16)
__global__ void k_meta(const int* __restrict__ degi, const int* __restrict__ x,
                       float* __restrict__ dinv, unsigned* __restrict__ packed) {
    int n = blockIdx.x * 256 + threadIdx.x;
    if (n < N_NODES) {
        float dv = rsqrtf((float)(degi[n] + 1));
        dinv[n] = dv;
        packed[n] = ((unsigned)f2bf(dv) << 16) | (unsigned)x[n];
    }
}

// scan 1563 bucket counts; init bbase
__global__ void k_bscan(const int* __restrict__ bcnt, int* __restrict__ bbase) {
    __shared__ int s[2048];
    int tid = threadIdx.x;
    int p0 = tid, p1 = tid + 1024;
    int v0 = (p0 < NBUCK) ? bcnt[p0] : 0;
    int v1 = (p1 < NBUCK) ? bcnt[p1] : 0;
    s[p0] = v0; s[p1] = v1;
    __syncthreads();
    for (int off = 1; off < 2048; off <<= 1) {
        int t0 = (p0 >= off) ? s[p0 - off] : 0;
        int t1 = (p1 >= off) ? s[p1 - off] : 0;
        __syncthreads();
        s[p0] += t0; s[p1] += t1;
        __syncthreads();
    }
    if (p0 < NBUCK) bbase[p0] = s[p0] - v0;
    if (p1 < NBUCK) bbase[p1] = s[p1] - v1;
    if (tid == 0) bbase[NBUCK] = N_EDGES;
}

// MERGED binB + layer-0 (R16): per 64-node bucket:
//   1. node scan from GLOBAL degi (no histogram pass)
//   2. gather 256 block-segments -> LDS slice (single staging read)
//   3. ONE fused loop: node-sort -> sorted_e  AND  S-bin accumulation
//      (S[n,v] += dinv_bf16[src] for x[src]==v; incl. self-loop)
//   4. h = bf16(relu(dinv*(S@M) + b));  q = offset-fp8(16*dinv*h)
// Replaces old k_binB + k_gather0_mfma; deletes the 12.8MB sorted_e re-read.
__global__ __launch_bounds__(256) void k_bg(
    const int* __restrict__ staging, const int* __restrict__ blkstart,
    const int* __restrict__ bbase, const int* __restrict__ degi,
    const unsigned* __restrict__ packed, const float* __restrict__ M,
    const float* __restrict__ dinv, const float* __restrict__ bias,
    int* __restrict__ sorted_e, int* __restrict__ row_start,
    unsigned short* __restrict__ h, unsigned char* __restrict__ qout) {
    __shared__ int lde[BUCK_NODES];
    __shared__ int lsc[BUCK_NODES];
    __shared__ int s2[PART_BLOCKS];
    __shared__ int sl[BIN_CAP];
    __shared__ float Sbins[G0_TILE][SBINS_STRIDE];
    __shared__ _Float16 Sb[G0_TILE][SB_STRIDE];
    __shared__ _Float16 Blds[H][SB_STRIDE];

    int b = blockIdx.x, tid = threadIdx.x;
    int n0 = b << BUCK_BITS;
    int s0 = bbase[b], s1v = bbase[b + 1];
    int total = s1v - s0;
    bool fit = (total <= BIN_CAP);

    for (int i = tid; i < G0_TILE * SBINS_STRIDE; i += 256)
        ((float*)Sbins)[i] = 0.0f;
    {
        int c = tid & 63, v0 = tid >> 6;
        for (int v = v0; v < VOCAB; v += 4)
            Blds[c][v] = (_Float16)M[v * H + c];
        Blds[c][VOCAB + v0] = (_Float16)0.0f;
    }

    const int* brow = blkstart + (size_t)tid * BS_STRIDE;
    int st = brow[b];
    int cnt = brow[b + 1] - st;
    s2[tid] = cnt;
    if (tid < BUCK_NODES) {
        int n = n0 + tid;
        lde[tid] = (n < N_NODES) ? degi[n] : 0;
    }
    __syncthreads();
    // segment-count scan -> segment offsets in slice
    for (int off = 1; off < PART_BLOCKS; off <<= 1) {
        int v = (tid >= off) ? s2[tid - off] : 0;
        __syncthreads();
        s2[tid] += v;
        __syncthreads();
    }
    int excl2 = s2[tid] - cnt;
    // node-degree scan -> per-node offsets
    if (tid < BUCK_NODES) lsc[tid] = lde[tid];
    __syncthreads();
    for (int off = 1; off < BUCK_NODES; off <<= 1) {
        int v = (tid >= off && tid < BUCK_NODES) ? lsc[tid - off] : 0;
        __syncthreads();
        if (tid < BUCK_NODES) lsc[tid] += v;
        __syncthreads();
    }
    if (tid < BUCK_NODES) {
        int n = n0 + tid;
        int ex = lsc[tid] - lde[tid];
        if (n < N_NODES) row_start[n] = s0 + ex;
        lsc[tid] = ex;
        lde[tid] = 0;   // becomes rank counters
    }
    // load slice (single global read of this bucket's entries)
    if (fit) {
        for (int i = 0; i < cnt; ++i) sl[excl2 + i] = staging[st + i];
    }
    __syncthreads();

    // self-loop terms
    if (tid < G0_TILE) {
        int n = n0 + tid;
        if (n < N_NODES) {
            unsigned p = packed[n];
            atomicAdd(&Sbins[tid][p & 127u], __uint_as_float(p & 0xffff0000u));
        }
    }
    // fused node-sort + S-accumulation
    if (fit) {
        for (int i = tid; i < total; i += 256) {
            int p = sl[i];
            int ln = p >> 17;
            int r = atomicAdd(&lde[ln], 1);
            sorted_e[s0 + lsc[ln] + r] = p;
            unsigned k = packed[p & 0x1FFFF];
            atomicAdd(&Sbins[ln][k & 127u], __uint_as_float(k & 0xffff0000u));
        }
    } else {
        for (int i = 0; i < cnt; ++i) {
            int p = staging[st + i];
            int ln = p >> 17;
            int r = atomicAdd(&lde[ln], 1);
            sorted_e[s0 + lsc[ln] + r] = p;
            unsigned k = packed[p & 0x1FFFF];
            atomicAdd(&Sbins[ln][k & 127u], __uint_as_float(k & 0xffff0000u));
        }
    }
    __syncthreads();

    // convert bins f32 -> f16 A-tile (each thread: 24 elems of one row)
    {
        int r0 = tid >> 2, k0 = (tid & 3) * 24;
#pragma unroll
        for (int m = 0; m < 3; ++m) {
            f32x4 f0 = *(const f32x4*)&Sbins[r0][k0 + 8 * m];
            f32x4 f1 = *(const f32x4*)&Sbins[r0][k0 + 8 * m + 4];
            half8 o;
            o[0] = (_Float16)f0[0]; o[1] = (_Float16)f0[1];
            o[2] = (_Float16)f0[2]; o[3] = (_Float16)f0[3];
            o[4] = (_Float16)f1[0]; o[5] = (_Float16)f1[1];
            o[6] = (_Float16)f1[2]; o[7] = (_Float16)f1[3];
            *(half8*)&Sb[r0][k0 + 8 * m] = o;
        }
    }
    __syncthreads();

    int w = tid >> 6, lane = tid & 63;
    int l15 = lane & 15, l4 = lane >> 4;
    half8 afr[3];
#pragma unroll
    for (int ks = 0; ks < 3; ++ks)
        afr[ks] = *(const half8*)&Sb[(w << 4) + l15][ks * 32 + l4 * 8];

    f32x4 acc[4];
#pragma unroll
    for (int c = 0; c < 4; ++c) {
        f32x4 a = {0.0f, 0.0f, 0.0f, 0.0f};
#pragma unroll
        for (int ks = 0; ks < 3; ++ks) {
            half8 bfr = *(const half8*)&Blds[c * 16 + l15][ks * 32 + l4 * 8];
            a = __builtin_amdgcn_mfma_f32_16x16x32_f16(afr[ks], bfr, a, 0, 0, 0);
        }
        acc[c] = a;
    }

    int rbase = (w << 4) + l4 * 4;
    float di4[4];
#pragma unroll
    for (int r = 0; r < 4; ++r) {
        int n = n0 + rbase + r;
        di4[r] = (n < N_NODES) ? dinv[n] : 0.0f;
    }
#pragma unroll
    for (int c = 0; c < 4; ++c) {
        float bb = bias[c * 16 + l15];
#pragma unroll
        for (int r = 0; r < 4; ++r) {
            int n = n0 + rbase + r;
            if (n < N_NODES) {
                float v = fmaxf(acc[c][r] * di4[r] + bb, 0.0f);
                h[(size_t)n * H + c * 16 + l15] = f2bf(v);
                qout[(size_t)n * H + c * 16 + l15] = fp8e(16.0f * di4[r] * v);
            }
        }
    }
}

// fused GCN layer (layers 1,2), offset-fp8 q, packed f16 decode, 32-edge
// pipeline (8 x uint2 in flight; VGPR headroom after packing, R15: 20 VGPR):
//   A[n,:] = sum_{e->n} q~[src] + q~[n] - n_terms*2^-6   (offset cancellation)
//   z = A @ W;  h = bf16(h + relu(dinv/16 * z + b));  qout = fp8(16*dinv*h')
__global__ __launch_bounds__(512) void k_fused(
    const int* __restrict__ sorted_e, const int* __restrict__ row_start,
    const int* __restrict__ degi, const unsigned char* __restrict__ q,
    const float* __restrict__ dinv, const float* __restrict__ W,
    const float* __restrict__ bias, unsigned short* __restrict__ h,
    unsigned char* __restrict__ qout, int last) {
    __shared__ _Float16 Alds[FL_TILE][A_STRIDE];
    __shared__ _Float16 Blds[H][A_STRIDE];

    int tid = threadIdx.x;
    int n0 = blockIdx.x * FL_TILE;

    // stage B = W^T in f16 (B frag: lane l -> B[k][l&15], k-contiguous 8)
    {
        int c = tid & 63, k0 = (tid >> 6) * 8;
#pragma unroll
        for (int k = 0; k < 8; ++k)
            Blds[c][k0 + k] = (_Float16)W[(k0 + k) * H + c];
    }

    int w = tid >> 6, lane = tid & 63;
    int s = lane >> 3;   // edge slot 0..7
    int j = lane & 7;    // 8B granule within row (channels 8j..8j+7)
    const uint2* q2 = (const uint2*)q;

    // gather phase: wave w owns nodes w*8..w*8+7; 32 edges in flight + prefetch
    for (int ni = 0; ni < 8; ++ni) {
        int nl = (w << 3) + ni;
        int n = n0 + nl;
        int d = 0, st = 0;
        if (n < N_NODES) { d = degi[n]; st = row_start[n]; }
        const int* srp = sorted_e + st;
        half2t a[4];
#pragma unroll
        for (int k = 0; k < 4; ++k) a[k] = ph(0u);

        // prime the index pipeline (safe: 64-int zero pad past N_EDGES)
        int sr0 = srp[s], sr1 = srp[8 + s], sr2 = srp[16 + s], sr3 = srp[24 + s];
        int e = 0;
        for (; e + 32 <= d; e += 32) {
            uint2 v0 = q2[(size_t)(sr0 & 0x1FFFF) * 8 + j];
            uint2 v1 = q2[(size_t)(sr1 & 0x1FFFF) * 8 + j];
            uint2 v2 = q2[(size_t)(sr2 & 0x1FFFF) * 8 + j];
            uint2 v3 = q2[(size_t)(sr3 & 0x1FFFF) * 8 + j];
            sr0 = srp[e + 32 + s]; sr1 = srp[e + 40 + s];
            sr2 = srp[e + 48 + s]; sr3 = srp[e + 56 + s];
            unpack_add8(v0, a); unpack_add8(v1, a);
            unpack_add8(v2, a); unpack_add8(v3, a);
        }
        if (e < d) {  // masked tail: code 8 = raw 2^-6 = pure offset (cancels)
            uint2 v0 = q2[(size_t)(sr0 & 0x1FFFF) * 8 + j];
            uint2 v1 = q2[(size_t)(sr1 & 0x1FFFF) * 8 + j];
            uint2 v2 = q2[(size_t)(sr2 & 0x1FFFF) * 8 + j];
            uint2 v3 = q2[(size_t)(sr3 & 0x1FFFF) * 8 + j];
            if (e + s >= d)      { v0.x = 0x08080808u; v0.y = 0x08080808u; }
            if (e + 8 + s >= d)  { v1.x = 0x08080808u; v1.y = 0x08080808u; }
            if (e + 16 + s >= d) { v2.x = 0x08080808u; v2.y = 0x08080808u; }
            if (e + 24 + s >= d) { v3.x = 0x08080808u; v3.y = 0x08080808u; }
            unpack_add8(v0, a); unpack_add8(v1, a);
            unpack_add8(v2, a); unpack_add8(v3, a);
        }
        // reduce across the 8 slots (packed f16 adds)
#pragma unroll
        for (int k = 0; k < 4; ++k) a[k] += ph(__shfl_xor(hu(a[k]), 8, 64));
#pragma unroll
        for (int k = 0; k < 4; ++k) a[k] += ph(__shfl_xor(hu(a[k]), 16, 64));
#pragma unroll
        for (int k = 0; k < 4; ++k) a[k] += ph(__shfl_xor(hu(a[k]), 32, 64));
        if (s == 0) {
            half8 o;
            if (n < N_NODES) {
                uint2 vs = q2[(size_t)n * 8 + j];   // self-loop term
                unpack_add8(vs, a);
                // offset cancellation: 32*ceil(d/32)+1 raw terms, each +2^-6
                int nch = (d + 31) >> 5;
                _Float16 corr = (_Float16)((float)(32 * nch + 1) * 0.015625f);
                half2t c2 = {corr, corr};
                half2t e0 = a[0] - c2, o0 = a[1] - c2;
                half2t e1 = a[2] - c2, o1 = a[3] - c2;
                o[0] = e0[0]; o[1] = o0[0]; o[2] = e0[1]; o[3] = o0[1];
                o[4] = e1[0]; o[5] = o1[0]; o[6] = e1[1]; o[7] = o1[1];
            } else {
#pragma unroll
                for (int k = 0; k < 8; ++k) o[k] = (_Float16)0.0f;
            }
            *(half8*)&Alds[nl][j * 8] = o;
        }
    }
    __syncthreads();

    // MFMA: wave w -> output rows [(w&3)*16, +16) x cols [(w>>2)*32, +32); K=64
    int l15 = lane & 15, l4 = lane >> 4;
    int rw = (w & 3) << 4;       // row base
    int cb = (w >> 2) << 1;      // col block base (of 16-wide col groups)
    half8 afr[2];
#pragma unroll
    for (int ks = 0; ks < 2; ++ks)
        afr[ks] = *(const half8*)&Alds[rw + l15][ks * 32 + l4 * 8];

    f32x4 acc[2];
#pragma unroll
    for (int ci = 0; ci < 2; ++ci) {
        f32x4 a = {0.0f, 0.0f, 0.0f, 0.0f};
#pragma unroll
        for (int ks = 0; ks < 2; ++ks) {
            half8 bfr = *(const half8*)&Blds[(cb + ci) * 16 + l15][ks * 32 + l4 * 8];
            a = __builtin_amdgcn_mfma_f32_16x16x32_f16(afr[ks], bfr, a, 0, 0, 0);
        }
        acc[ci] = a;
    }

    // epilogue: h = bf16(h + relu(acc*(dinv/16) + b)); qout = fp8(16*dinv*h')
    int rbase = rw + l4 * 4;
    float di4[4];
#pragma unroll
    for (int r = 0; r < 4; ++r) {
        int n = n0 + rbase + r;
        di4[r] = (n < N_NODES) ? dinv[n] : 0.0f;
    }
#pragma unroll
    for (int ci = 0; ci < 2; ++ci) {
        float bb = bias[(cb + ci) * 16 + l15];
#pragma unroll
        for (int r = 0; r < 4; ++r) {
            int n = n0 + rbase + r;
            if (n < N_NODES) {
                size_t idx = (size_t)n * H + (cb + ci) * 16 + l15;
                float v = bf2f(h[idx]) +
                          fmaxf(acc[ci][r] * (di4[r] * 0.0625f) + bb, 0.0f);
                h[idx] = f2bf(v);
                if (!last) qout[idx] = fp8e(16.0f * di4[r] * v);
            }
        }
    }
}

// fused mean-pool + MLP: 256 threads (8 half-waves) per graph.
__global__ __launch_bounds__(256) void k_poolmlp(
    const unsigned short* __restrict__ h, const int* __restrict__ batch,
    const float* __restrict__ w1, const float* __restrict__ b1,
    const float* __restrict__ w2, const float* __restrict__ b2,
    const float* __restrict__ w3, const float* __restrict__ b3,
    float* __restrict__ out) {
    __shared__ float2 part[8][32];
    __shared__ float sg[H];
    __shared__ float s1[32];
    __shared__ float s2[16];
    int g = blockIdx.x, tid = threadIdx.x;
    int lo = 0, hi = N_NODES;
    while (lo < hi) { int mid = (lo + hi) >> 1; if (batch[mid] < g) lo = mid + 1; else hi = mid; }
    int lo2 = lo, hi2 = N_NODES;
    while (lo2 < hi2) { int mid = (lo2 + hi2) >> 1; if (batch[mid] < g + 1) lo2 = mid + 1; else hi2 = mid; }

    int hw = tid >> 5;
    int c = tid & 31;
    const unsigned* h2 = (const unsigned*)h;
    float ax = 0.0f, ay = 0.0f;
    for (int n = lo + hw; n < lo2; n += 8) {
        unsigned u = h2[(size_t)n * 32 + c];
        ax += bflo(u); ay += bfhi(u);
    }
    part[hw][c] = make_float2(ax, ay);
    __syncthreads();
    if (tid < 32) {
        float sx = 0.0f, sy = 0.0f;
#pragma unroll
        for (int k = 0; k < 8; ++k) { sx += part[k][tid].x; sy += part[k][tid].y; }
        float cntf = fmaxf((float)(lo2 - lo), 1.0f);
        sg[2 * tid] = sx / cntf;
        sg[2 * tid + 1] = sy / cntf;
    }
    __syncthreads();
    if (tid < 32) {
        float a = b1[tid];
#pragma unroll
        for (int k = 0; k < H; ++k) a += sg[k] * w1[k * 32 + tid];
        s1[tid] = fmaxf(a, 0.0f);
    }
    __syncthreads();
    if (tid < 16) {
        float a = b2[tid];
#pragma unroll
        for (int k = 0; k < 32; ++k) a += s1[k] * w2[k * 16 + tid];
        s2[tid] = fmaxf(a, 0.0f);
    }
    __syncthreads();
    if (tid == 0) {
        float a = b3[0];
#pragma unroll
        for (int k = 0; k < 16; ++k) a += s2[k] * w3[k];
        out[g] = a;
    }
}

// ---------------- launch ----------------

extern "C" void kernel_launch(void* const* d_in, const int* in_sizes, int n_in,
                              void* d_out, int out_size, void* d_ws, size_t ws_size,
                              hipStream_t stream) {
    const int*   x      = (const int*)d_in[0];
    const int*   eidx   = (const int*)d_in[1];   // (2, E): row = eidx, col = eidx + E
    const int*   batch  = (const int*)d_in[2];
    const float* emb    = (const float*)d_in[3];
    const float* conv_w = (const float*)d_in[4];
    const float* conv_b = (const float*)d_in[5];
    const float* w1     = (const float*)d_in[6];
    const float* b1     = (const float*)d_in[7];
    const float* w2     = (const float*)d_in[8];
    const float* b2     = (const float*)d_in[9];
    const float* w3     = (const float*)d_in[10];
    const float* b3     = (const float*)d_in[11];
    float* out = (float*)d_out;

    const int* row = eidx;
    const int* col = eidx + N_EDGES;

    // workspace layout (4-byte units)
    char* wsb = (char*)d_ws;
    size_t off = 0;
    auto alloc = [&](size_t elems) { void* p = wsb + off; off += ((elems * 4 + 255) & ~(size_t)255); return p; };
    int*      bcnt       = (int*)alloc(NBUCK);
    int*      bbase      = (int*)alloc(NBUCK + 1);
    int*      blkstart   = (int*)alloc((size_t)PART_BLOCKS * BS_STRIDE);
    int*      row_start  = (int*)alloc(N_NODES);
    int*      degi       = (int*)alloc(N_NODES);
    float*    dinv       = (float*)alloc(N_NODES);
    unsigned* packed     = (unsigned*)alloc(N_NODES);
    float*    M          = (float*)alloc(VOCAB * H);
    int*      sorted_e   = (int*)alloc(N_EDGES + 64);            // +64 zero pad
    unsigned short* h    = (unsigned short*)alloc((size_t)N_NODES * H / 2);  // bf16
    // qa region doubles as block-major staging (12.8 MB); q itself needs 6.4 MB
    unsigned char* qa    = (unsigned char*)alloc((size_t)N_EDGES);           // 12.8 MB
    unsigned char* qb    = (unsigned char*)alloc((size_t)N_NODES * H / 4);   // 6.4 MB

    // block-major staging aliases qa: written by binA, read by k_bg only.
    // qa is first written (as fp8 q) by k_fused layer 1, after k_bg completes.
    int* staging = (int*)qa;

    const int gF = (N_NODES + FL_TILE - 1) / FL_TILE;   // 1563

    hipLaunchKernelGGL(k_pre, dim3(VOCAB), dim3(H), 0, stream,
                       emb, conv_w, M, bcnt, sorted_e + N_EDGES, degi);
    hipLaunchKernelGGL(k_binA, dim3(PART_BLOCKS), dim3(1024), 0, stream,
                       row, col, bcnt, blkstart, staging, degi);
    hipLaunchKernelGGL(k_meta, dim3((N_NODES + 255) / 256), dim3(256), 0, stream,
                       degi, x, dinv, packed);
    hipLaunchKernelGGL(k_bscan, dim3(1), dim3(1024), 0, stream, bcnt, bbase);

    // merged binB + layer-0: sorts to sorted_e AND computes h + q(->qb, fp8)
    hipLaunchKernelGGL(k_bg, dim3(NBUCK), dim3(256), 0, stream,
                       staging, blkstart, bbase, degi, packed, M, dinv, conv_b,
                       sorted_e, row_start, h, qb);

    // layers 1,2: fused gather + MFMA transform (h@W commutes with aggregation)
    hipLaunchKernelGGL(k_fused, dim3(gF), dim3(512), 0, stream,
                       sorted_e, row_start, degi, qb, dinv,
                       conv_w + (size_t)1 * H * H, conv_b + 1 * H, h, qa, 0);
    hipLaunchKernelGGL(k_fused, dim3(gF), dim3(512), 0, stream,
                       sorted_e, row_start, degi, qa, dinv,
                       conv_w + (size_t)2 * H * H, conv_b + 2 * H, h, qb, 1);

    hipLaunchKernelGGL(k_poolmlp, dim3(N_GRAPHS), dim3(256), 0, stream,
                       h, batch, w1, b1, w2, b2, w3, b3, out);

    (void)in_sizes; (void)n_in; (void)out_size; (void)ws_size;
}

// Round 19
// 321.677 us; speedup vs baseline: 1.4088x; 1.4088x over previous
//
#include <hip/hip_runtime.h>

#define N_NODES 100000
#define N_EDGES 3200000
#define N_GRAPHS 2048
#define VOCAB 92
#define H 64
#define N_LAYERS 3

#define BUCK_BITS 6
#define BUCK_NODES (1 << BUCK_BITS)                          // 64 nodes / bucket
#define NBUCK ((N_NODES + BUCK_NODES - 1) / BUCK_NODES)      // 1563

#define PART_BLOCKS 256                                      // == binB blockDim!
#define EDGES_PER_PART (N_EDGES / PART_BLOCKS)               // 12500
#define BS_STRIDE (NBUCK + 1)                                // blkstart row stride

#define BIN_CAP 2560       // LDS slice cap: bucket load ~Poisson(2048), max≈2256

// layer-0 MFMA kernel geometry (tile == bucket == 64 nodes)
#define G0_TILE 64
#define SBINS_STRIDE 100   // f32 bins stride (92 used, pad to break banks)
#define SB_STRIDE 104      // f16 tile stride (92->96 K-pad, +8 bank pad)

// fused layer kernel geometry
#define FL_TILE 64
#define A_STRIDE 72        // f16 LDS stride (64 + 8 pad -> 2-way banks, free)

typedef _Float16 half8 __attribute__((ext_vector_type(8)));
typedef _Float16 half2t __attribute__((ext_vector_type(2)));
typedef float f32x4 __attribute__((ext_vector_type(4)));

// fp32 -> bf16 (round-to-nearest-even)
__device__ inline unsigned short f2bf(float f) {
    union { float f; unsigned u; } v; v.f = f;
    unsigned u = v.u;
    u += 0x7fffu + ((u >> 16) & 1u);
    return (unsigned short)(u >> 16);
}
__device__ inline float bfhi(unsigned p) {
    union { unsigned u; float f; } v; v.u = p & 0xffff0000u; return v.f;
}
__device__ inline float bflo(unsigned p) {
    union { unsigned u; float f; } v; v.u = p << 16; return v.f;
}
__device__ inline float bf2f(unsigned short b) {
    union { unsigned u; float f; } v; v.u = ((unsigned)b) << 16; return v.f;
}

// ---- OFFSET-BINADE fp8 (bias 7): code = e4m3(v + 2^-6), v >= 0.
// Every code is NORMAL (offset kills denormals). f16 decode of code em is
//   f16raw = (em << 7) + 0x2000  ==  f32 decode ((em<<20)+0x3C000000) exactly.
// PACKED decode: two codes -> one half2 in 3 int ops; accumulate v_pk_add_f16.
// Offset removed exactly post-reduce (masked tail lanes inject code 8 = pure
// offset). R16 lesson: NO scattered global atomics (40x cost at XCD coherence
// point). R17/R18 lesson: depth-32 variant kills the container (4 attempts) —
// this is the proven 16-edge R15 configuration.

__device__ inline unsigned char fp8e(float v) {   // v >= 0, v < ~200
    union { float f; unsigned u; } a; a.f = v + 0.015625f;
    unsigned u = a.u + 0x0007FFFFu + ((a.u >> 20) & 1u);   // RNE into bit 20
    return (unsigned char)((u >> 20) - 960u);               // (e-120)<<3 | m3
}

__device__ inline half2t ph(unsigned u) {
    union { unsigned u; half2t h; } t; t.u = u; return t.h;
}
__device__ inline unsigned hu(half2t h) {
    union { half2t h; unsigned u; } t; t.h = h; return t.u;
}

// decode+accumulate 8 offset-fp8 codes (uint2):
//   a[0]+=(ch0,ch2) a[1]+=(ch1,ch3) a[2]+=(ch4,ch6) a[3]+=(ch5,ch7)
__device__ inline void unpack_add8(uint2 v, half2t* a) {
    a[0] += ph(((v.x & 0x00FF00FFu) << 7) + 0x20002000u);
    a[1] += ph(((v.x >> 1) & 0x7F807F80u) + 0x20002000u);
    a[2] += ph(((v.y & 0x00FF00FFu) << 7) + 0x20002000u);
    a[3] += ph(((v.y >> 1) & 0x7F807F80u) + 0x20002000u);
}

// ---------------- kernels ----------------

// merged: M = emb @ W0 (one block per vocab row) + zero bcnt/srpad.
__global__ void k_pre(const float* __restrict__ emb, const float* __restrict__ W0,
                      float* __restrict__ M, int* __restrict__ bcnt,
                      int* __restrict__ srpad) {
    int v = blockIdx.x, c = threadIdx.x;
    int i = v * 64 + c;
    if (i < NBUCK) bcnt[i] = 0;
    if (v == 0 && c < 64) srpad[c] = 0;
    float acc = 0.0f;
#pragma unroll
    for (int k = 0; k < H; ++k) acc += emb[v * H + k] * W0[k * H + c];
    M[v * H + c] = acc;
}

// binA (block-major): each block counting-sorts its chunk by bucket into ITS
// OWN contiguous staging region. One writer/XCD per line -> write amp ~x1.
__global__ __launch_bounds__(1024) void k_binA(const int* __restrict__ row,
                                               const int* __restrict__ col,
                                               int* __restrict__ bcnt,
                                               int* __restrict__ blkstart,
                                               int* __restrict__ staging) {
    __shared__ int lh[NBUCK];    // histogram, then rank counters
    __shared__ int lsc[NBUCK];   // exclusive scan (chunk-local offsets)
    __shared__ int s[2048];      // scan workspace
    int tid = threadIdx.x;
    int base = blockIdx.x * EDGES_PER_PART;

    for (int i = tid; i < NBUCK; i += 1024) lh[i] = 0;
    __syncthreads();
    for (int k = tid; k < EDGES_PER_PART; k += 1024)
        atomicAdd(&lh[col[base + k] >> BUCK_BITS], 1);
    __syncthreads();

    int p0 = tid, p1 = tid + 1024;
    int v0 = (p0 < NBUCK) ? lh[p0] : 0;
    int v1 = (p1 < NBUCK) ? lh[p1] : 0;
    s[p0] = v0; s[p1] = v1;
    __syncthreads();
    for (int off = 1; off < 2048; off <<= 1) {
        int t0 = (p0 >= off) ? s[p0 - off] : 0;
        int t1 = (p1 >= off) ? s[p1 - off] : 0;
        __syncthreads();
        s[p0] += t0; s[p1] += t1;
        __syncthreads();
    }
    int* myrow = blkstart + (size_t)blockIdx.x * BS_STRIDE;
    if (p0 < NBUCK) {
        int e = s[p0] - v0;
        lsc[p0] = e;
        myrow[p0] = base + e;
        if (v0) atomicAdd(&bcnt[p0], v0);
        lh[p0] = 0;
    }
    if (p1 < NBUCK) {
        int e = s[p1] - v1;
        lsc[p1] = e;
        myrow[p1] = base + e;
        if (v1) atomicAdd(&bcnt[p1], v1);
        lh[p1] = 0;
    }
    if (tid == 0) myrow[NBUCK] = base + EDGES_PER_PART;
    __syncthreads();

    for (int k = tid; k < EDGES_PER_PART; k += 1024) {
        int c = col[base + k];
        int b = c >> BUCK_BITS;
        int r = atomicAdd(&lh[b], 1);
        staging[base + lsc[b] + r] = row[base + k] | ((c & (BUCK_NODES - 1)) << 17);
    }
}

// scan 1563 bucket counts; init bbase
__global__ void k_bscan(const int* __restrict__ bcnt, int* __restrict__ bbase) {
    __shared__ int s[2048];
    int tid = threadIdx.x;
    int p0 = tid, p1 = tid + 1024;
    int v0 = (p0 < NBUCK) ? bcnt[p0] : 0;
    int v1 = (p1 < NBUCK) ? bcnt[p1] : 0;
    s[p0] = v0; s[p1] = v1;
    __syncthreads();
    for (int off = 1; off < 2048; off <<= 1) {
        int t0 = (p0 >= off) ? s[p0 - off] : 0;
        int t1 = (p1 >= off) ? s[p1 - off] : 0;
        __syncthreads();
        s[p0] += t0; s[p1] += t1;
        __syncthreads();
    }
    if (p0 < NBUCK) bbase[p0] = s[p0] - v0;
    if (p1 < NBUCK) bbase[p1] = s[p1] - v1;
    if (tid == 0) bbase[NBUCK] = N_EDGES;
}

// binB: gather bucket's 256 segments into LDS, degree hist/scan -> node data,
// then node-sort into sorted_e (full entries: row | ln<<17).
__global__ __launch_bounds__(256) void k_binB(const int* __restrict__ staging,
                                              const int* __restrict__ blkstart,
                                              const int* __restrict__ bbase,
                                              const int* __restrict__ x,
                                              int* __restrict__ sorted_e,
                                              int* __restrict__ degi,
                                              int* __restrict__ row_start,
                                              float* __restrict__ dinv,
                                              unsigned* __restrict__ packed) {
    __shared__ int lde[BUCK_NODES];
    __shared__ int lsc[BUCK_NODES];
    __shared__ int sl[BIN_CAP];
    __shared__ int s2[PART_BLOCKS];
    int b = blockIdx.x, tid = threadIdx.x;
    int n0 = b << BUCK_BITS;
    int s0 = bbase[b], s1 = bbase[b + 1];
    int total = s1 - s0;
    bool fit = (total <= BIN_CAP);

    const int* brow = blkstart + (size_t)tid * BS_STRIDE;
    int st = brow[b];
    int cnt = brow[b + 1] - st;

    if (tid < BUCK_NODES) lde[tid] = 0;
    s2[tid] = cnt;
    __syncthreads();
    for (int off = 1; off < PART_BLOCKS; off <<= 1) {
        int v = (tid >= off) ? s2[tid - off] : 0;
        __syncthreads();
        s2[tid] += v;
        __syncthreads();
    }
    int excl = s2[tid] - cnt;

    if (fit) {
        for (int i = 0; i < cnt; ++i) {
            int p = staging[st + i];
            sl[excl + i] = p;
            atomicAdd(&lde[p >> 17], 1);
        }
    } else {
        for (int i = 0; i < cnt; ++i)
            atomicAdd(&lde[staging[st + i] >> 17], 1);
    }
    __syncthreads();

    if (tid < BUCK_NODES) lsc[tid] = lde[tid];
    __syncthreads();
    for (int off = 1; off < BUCK_NODES; off <<= 1) {
        int v = (tid >= off && tid < BUCK_NODES) ? lsc[tid - off] : 0;
        __syncthreads();
        if (tid < BUCK_NODES) lsc[tid] += v;
        __syncthreads();
    }
    if (tid < BUCK_NODES) {
        int n = n0 + tid;
        int ex = lsc[tid] - lde[tid];
        if (n < N_NODES) {
            row_start[n] = s0 + ex;
            degi[n] = lde[tid];
            float dv = rsqrtf((float)(lde[tid] + 1));
            dinv[n] = dv;
            packed[n] = ((unsigned)f2bf(dv) << 16) | (unsigned)x[n];
        }
        lsc[tid] = ex;
        lde[tid] = 0;
    }
    __syncthreads();
    if (fit) {
        for (int i = tid; i < total; i += 256) {
            int p = sl[i];
            int ln = p >> 17;
            int r = atomicAdd(&lde[ln], 1);
            sorted_e[s0 + lsc[ln] + r] = p;
        }
    } else {
        for (int i = 0; i < cnt; ++i) {
            int p = staging[st + i];
            int ln = p >> 17;
            int r = atomicAdd(&lde[ln], 1);
            sorted_e[s0 + lsc[ln] + r] = p;
        }
    }
}

// layer-0, vocab-factored, streaming sorted_e:
//   h = bf16(relu(dinv*(S@M) + b));  q = offset-fp8(16 * dinv * h)
__global__ __launch_bounds__(256) void k_gather0_mfma(
    const int* __restrict__ sorted_e, const int* __restrict__ bbase,
    const unsigned* __restrict__ packed,
    const float* __restrict__ M, const float* __restrict__ dinv,
    const float* __restrict__ bias, unsigned short* __restrict__ h,
    unsigned char* __restrict__ qout) {
    __shared__ float Sbins[G0_TILE][SBINS_STRIDE];
    __shared__ _Float16 Sb[G0_TILE][SB_STRIDE];
    __shared__ _Float16 Blds[H][SB_STRIDE];

    int tid = threadIdx.x;
    int b = blockIdx.x;
    int n0 = b << BUCK_BITS;

    for (int i = tid; i < G0_TILE * SBINS_STRIDE; i += 256)
        ((float*)Sbins)[i] = 0.0f;
    {
        int c = tid & 63, v0 = tid >> 6;
        for (int v = v0; v < VOCAB; v += 4)
            Blds[c][v] = (_Float16)M[v * H + c];
        Blds[c][VOCAB + v0] = (_Float16)0.0f;
    }
    __syncthreads();

    if (tid < G0_TILE) {
        int n = n0 + tid;
        if (n < N_NODES) {
            unsigned p = packed[n];
            atomicAdd(&Sbins[tid][p & 127u], __uint_as_float(p & 0xffff0000u));
        }
    }
    {
        int s0 = bbase[b], s1 = bbase[b + 1];
        int i = s0 + tid;
        for (; i + 256 < s1; i += 512) {
            int p0 = sorted_e[i];
            int p1 = sorted_e[i + 256];
            unsigned k0 = packed[p0 & 0x1FFFF];
            unsigned k1 = packed[p1 & 0x1FFFF];
            atomicAdd(&Sbins[p0 >> 17][k0 & 127u], __uint_as_float(k0 & 0xffff0000u));
            atomicAdd(&Sbins[p1 >> 17][k1 & 127u], __uint_as_float(k1 & 0xffff0000u));
        }
        if (i < s1) {
            int p0 = sorted_e[i];
            unsigned k0 = packed[p0 & 0x1FFFF];
            atomicAdd(&Sbins[p0 >> 17][k0 & 127u], __uint_as_float(k0 & 0xffff0000u));
        }
    }
    __syncthreads();

    {
        int r0 = tid >> 2, k0 = (tid & 3) * 24;
#pragma unroll
        for (int m = 0; m < 3; ++m) {
            f32x4 f0 = *(const f32x4*)&Sbins[r0][k0 + 8 * m];
            f32x4 f1 = *(const f32x4*)&Sbins[r0][k0 + 8 * m + 4];
            half8 o;
            o[0] = (_Float16)f0[0]; o[1] = (_Float16)f0[1];
            o[2] = (_Float16)f0[2]; o[3] = (_Float16)f0[3];
            o[4] = (_Float16)f1[0]; o[5] = (_Float16)f1[1];
            o[6] = (_Float16)f1[2]; o[7] = (_Float16)f1[3];
            *(half8*)&Sb[r0][k0 + 8 * m] = o;
        }
    }
    __syncthreads();

    int w = tid >> 6, lane = tid & 63;
    int l15 = lane & 15, l4 = lane >> 4;
    half8 afr[3];
#pragma unroll
    for (int ks = 0; ks < 3; ++ks)
        afr[ks] = *(const half8*)&Sb[(w << 4) + l15][ks * 32 + l4 * 8];

    f32x4 acc[4];
#pragma unroll
    for (int c = 0; c < 4; ++c) {
        f32x4 a = {0.0f, 0.0f, 0.0f, 0.0f};
#pragma unroll
        for (int ks = 0; ks < 3; ++ks) {
            half8 bfr = *(const half8*)&Blds[c * 16 + l15][ks * 32 + l4 * 8];
            a = __builtin_amdgcn_mfma_f32_16x16x32_f16(afr[ks], bfr, a, 0, 0, 0);
        }
        acc[c] = a;
    }

    int rbase = (w << 4) + l4 * 4;
    float di4[4];
#pragma unroll
    for (int r = 0; r < 4; ++r) {
        int n = n0 + rbase + r;
        di4[r] = (n < N_NODES) ? dinv[n] : 0.0f;
    }
#pragma unroll
    for (int c = 0; c < 4; ++c) {
        float bb = bias[c * 16 + l15];
#pragma unroll
        for (int r = 0; r < 4; ++r) {
            int n = n0 + rbase + r;
            if (n < N_NODES) {
                float v = fmaxf(acc[c][r] * di4[r] + bb, 0.0f);
                h[(size_t)n * H + c * 16 + l15] = f2bf(v);
                qout[(size_t)n * H + c * 16 + l15] = fp8e(16.0f * di4[r] * v);
            }
        }
    }
}

// fused GCN layer (layers 1,2), offset-fp8 q, PACKED f16 decode+accumulate:
//   A[n,:] = sum_{e->n} q~[src] + q~[n] - n_terms*2^-6   (offset cancellation)
//   z = A @ W;  h = bf16(h + relu(dinv/16 * z + b));  qout = fp8(16*dinv*h')
__global__ __launch_bounds__(512) void k_fused(
    const int* __restrict__ sorted_e, const int* __restrict__ row_start,
    const int* __restrict__ degi, const unsigned char* __restrict__ q,
    const float* __restrict__ dinv, const float* __restrict__ W,
    const float* __restrict__ bias, unsigned short* __restrict__ h,
    unsigned char* __restrict__ qout, int last) {
    __shared__ _Float16 Alds[FL_TILE][A_STRIDE];
    __shared__ _Float16 Blds[H][A_STRIDE];

    int tid = threadIdx.x;
    int n0 = blockIdx.x * FL_TILE;

    // stage B = W^T in f16 (B frag: lane l -> B[k][l&15], k-contiguous 8)
    {
        int c = tid & 63, k0 = (tid >> 6) * 8;
#pragma unroll
        for (int k = 0; k < 8; ++k)
            Blds[c][k0 + k] = (_Float16)W[(k0 + k) * H + c];
    }

    int w = tid >> 6, lane = tid & 63;
    int s = lane >> 3;   // edge slot 0..7
    int j = lane & 7;    // 8B granule within row (channels 8j..8j+7)
    const uint2* q2 = (const uint2*)q;

    // gather phase: wave w owns nodes w*8..w*8+7; 16 edges in flight + index prefetch
    for (int ni = 0; ni < 8; ++ni) {
        int nl = (w << 3) + ni;
        int n = n0 + nl;
        int d = 0, st = 0;
        if (n < N_NODES) { d = degi[n]; st = row_start[n]; }
        const int* srp = sorted_e + st;
        // packed accumulators: a[0]=(c0,c2) a[1]=(c1,c3) a[2]=(c4,c6) a[3]=(c5,c7)
        half2t a[4];
#pragma unroll
        for (int k = 0; k < 4; ++k) a[k] = ph(0u);

        // prime the index pipeline (safe: 64-int zero pad past N_EDGES)
        int srA = srp[s];
        int srB = srp[8 + s];
        int e = 0;
        for (; e + 16 <= d; e += 16) {
            uint2 va = q2[(size_t)(srA & 0x1FFFF) * 8 + j];
            uint2 vb = q2[(size_t)(srB & 0x1FFFF) * 8 + j];
            srA = srp[e + 16 + s];
            srB = srp[e + 24 + s];
            unpack_add8(va, a);
            unpack_add8(vb, a);
        }
        if (e < d) {  // masked tail: code 8 = raw 2^-6 = pure offset (cancels)
            uint2 va = q2[(size_t)(srA & 0x1FFFF) * 8 + j];
            uint2 vb = q2[(size_t)(srB & 0x1FFFF) * 8 + j];
            if (e + s >= d) { va.x = 0x08080808u; va.y = 0x08080808u; }
            if (e + 8 + s >= d) { vb.x = 0x08080808u; vb.y = 0x08080808u; }
            unpack_add8(va, a);
            unpack_add8(vb, a);
        }
        // reduce across the 8 slots (packed f16 adds: half the ops)
#pragma unroll
        for (int k = 0; k < 4; ++k) a[k] += ph(__shfl_xor(hu(a[k]), 8, 64));
#pragma unroll
        for (int k = 0; k < 4; ++k) a[k] += ph(__shfl_xor(hu(a[k]), 16, 64));
#pragma unroll
        for (int k = 0; k < 4; ++k) a[k] += ph(__shfl_xor(hu(a[k]), 32, 64));
        if (s == 0) {
            half8 o;
            if (n < N_NODES) {
                uint2 vs = q2[(size_t)n * 8 + j];   // self-loop term
                unpack_add8(vs, a);
                // offset cancellation: 16*ceil(d/16)+1 raw terms, each +2^-6
                int nch = (d + 15) >> 4;
                _Float16 corr = (_Float16)((float)(16 * nch + 1) * 0.015625f);
                half2t c2 = {corr, corr};
                half2t e0 = a[0] - c2, o0 = a[1] - c2;
                half2t e1 = a[2] - c2, o1 = a[3] - c2;
                o[0] = e0[0]; o[1] = o0[0]; o[2] = e0[1]; o[3] = o0[1];
                o[4] = e1[0]; o[5] = o1[0]; o[6] = e1[1]; o[7] = o1[1];
            } else {
#pragma unroll
                for (int k = 0; k < 8; ++k) o[k] = (_Float16)0.0f;
            }
            *(half8*)&Alds[nl][j * 8] = o;
        }
    }
    __syncthreads();

    // MFMA: wave w -> output rows [(w&3)*16, +16) x cols [(w>>2)*32, +32); K=64
    int l15 = lane & 15, l4 = lane >> 4;
    int rw = (w & 3) << 4;       // row base
    int cb = (w >> 2) << 1;      // col block base (of 16-wide col groups)
    half8 afr[2];
#pragma unroll
    for (int ks = 0; ks < 2; ++ks)
        afr[ks] = *(const half8*)&Alds[rw + l15][ks * 32 + l4 * 8];

    f32x4 acc[2];
#pragma unroll
    for (int ci = 0; ci < 2; ++ci) {
        f32x4 a = {0.0f, 0.0f, 0.0f, 0.0f};
#pragma unroll
        for (int ks = 0; ks < 2; ++ks) {
            half8 bfr = *(const half8*)&Blds[(cb + ci) * 16 + l15][ks * 32 + l4 * 8];
            a = __builtin_amdgcn_mfma_f32_16x16x32_f16(afr[ks], bfr, a, 0, 0, 0);
        }
        acc[ci] = a;
    }

    // epilogue: h = bf16(h + relu(acc*(dinv/16) + b)); qout = fp8(16*dinv*h')
    int rbase = rw + l4 * 4;
    float di4[4];
#pragma unroll
    for (int r = 0; r < 4; ++r) {
        int n = n0 + rbase + r;
        di4[r] = (n < N_NODES) ? dinv[n] : 0.0f;
    }
#pragma unroll
    for (int ci = 0; ci < 2; ++ci) {
        float bb = bias[(cb + ci) * 16 + l15];
#pragma unroll
        for (int r = 0; r < 4; ++r) {
            int n = n0 + rbase + r;
            if (n < N_NODES) {
                size_t idx = (size_t)n * H + (cb + ci) * 16 + l15;
                float v = bf2f(h[idx]) +
                          fmaxf(acc[ci][r] * (di4[r] * 0.0625f) + bb, 0.0f);
                h[idx] = f2bf(v);
                if (!last) qout[idx] = fp8e(16.0f * di4[r] * v);
            }
        }
    }
}

// fused mean-pool + MLP: 256 threads (8 half-waves) per graph.
__global__ __launch_bounds__(256) void k_poolmlp(
    const unsigned short* __restrict__ h, const int* __restrict__ batch,
    const float* __restrict__ w1, const float* __restrict__ b1,
    const float* __restrict__ w2, const float* __restrict__ b2,
    const float* __restrict__ w3, const float* __restrict__ b3,
    float* __restrict__ out) {
    __shared__ float2 part[8][32];
    __shared__ float sg[H];
    __shared__ float s1[32];
    __shared__ float s2[16];
    int g = blockIdx.x, tid = threadIdx.x;
    int lo = 0, hi = N_NODES;
    while (lo < hi) { int mid = (lo + hi) >> 1; if (batch[mid] < g) lo = mid + 1; else hi = mid; }
    int lo2 = lo, hi2 = N_NODES;
    while (lo2 < hi2) { int mid = (lo2 + hi2) >> 1; if (batch[mid] < g + 1) lo2 = mid + 1; else hi2 = mid; }

    int hw = tid >> 5;
    int c = tid & 31;
    const unsigned* h2 = (const unsigned*)h;
    float ax = 0.0f, ay = 0.0f;
    for (int n = lo + hw; n < lo2; n += 8) {
        unsigned u = h2[(size_t)n * 32 + c];
        ax += bflo(u); ay += bfhi(u);
    }
    part[hw][c] = make_float2(ax, ay);
    __syncthreads();
    if (tid < 32) {
        float sx = 0.0f, sy = 0.0f;
#pragma unroll
        for (int k = 0; k < 8; ++k) { sx += part[k][tid].x; sy += part[k][tid].y; }
        float cntf = fmaxf((float)(lo2 - lo), 1.0f);
        sg[2 * tid] = sx / cntf;
        sg[2 * tid + 1] = sy / cntf;
    }
    __syncthreads();
    if (tid < 32) {
        float a = b1[tid];
#pragma unroll
        for (int k = 0; k < H; ++k) a += sg[k] * w1[k * 32 + tid];
        s1[tid] = fmaxf(a, 0.0f);
    }
    __syncthreads();
    if (tid < 16) {
        float a = b2[tid];
#pragma unroll
        for (int k = 0; k < 32; ++k) a += s1[k] * w2[k * 16 + tid];
        s2[tid] = fmaxf(a, 0.0f);
    }
    __syncthreads();
    if (tid == 0) {
        float a = b3[0];
#pragma unroll
        for (int k = 0; k < 16; ++k) a += s2[k] * w3[k];
        out[g] = a;
    }
}

// ---------------- launch ----------------

extern "C" void kernel_launch(void* const* d_in, const int* in_sizes, int n_in,
                              void* d_out, int out_size, void* d_ws, size_t ws_size,
                              hipStream_t stream) {
    const int*   x      = (const int*)d_in[0];
    const int*   eidx   = (const int*)d_in[1];   // (2, E): row = eidx, col = eidx + E
    const int*   batch  = (const int*)d_in[2];
    const float* emb    = (const float*)d_in[3];
    const float* conv_w = (const float*)d_in[4];
    const float* conv_b = (const float*)d_in[5];
    const float* w1     = (const float*)d_in[6];
    const float* b1     = (const float*)d_in[7];
    const float* w2     = (const float*)d_in[8];
    const float* b2     = (const float*)d_in[9];
    const float* w3     = (const float*)d_in[10];
    const float* b3     = (const float*)d_in[11];
    float* out = (float*)d_out;

    const int* row = eidx;
    const int* col = eidx + N_EDGES;

    // workspace layout (4-byte units)
    char* wsb = (char*)d_ws;
    size_t off = 0;
    auto alloc = [&](size_t elems) { void* p = wsb + off; off += ((elems * 4 + 255) & ~(size_t)255); return p; };
    int*      bcnt       = (int*)alloc(NBUCK);
    int*      bbase      = (int*)alloc(NBUCK + 1);
    int*      blkstart   = (int*)alloc((size_t)PART_BLOCKS * BS_STRIDE);
    int*      row_start  = (int*)alloc(N_NODES);
    int*      degi       = (int*)alloc(N_NODES);
    float*    dinv       = (float*)alloc(N_NODES);
    unsigned* packed     = (unsigned*)alloc(N_NODES);
    float*    M          = (float*)alloc(VOCAB * H);
    int*      sorted_e   = (int*)alloc(N_EDGES + 64);            // +64 zero pad
    unsigned short* h    = (unsigned short*)alloc((size_t)N_NODES * H / 2);  // bf16
    // qa region doubles as block-major staging (12.8 MB); q itself needs 6.4 MB
    unsigned char* qa    = (unsigned char*)alloc((size_t)N_EDGES);           // 12.8 MB
    unsigned char* qb    = (unsigned char*)alloc((size_t)N_NODES * H / 4);   // 6.4 MB

    // block-major staging aliases qa: written by binA, read by binB only.
    // qa is first written (as fp8 q) by k_fused layer 1, after binB completes.
    int* staging = (int*)qa;

    const int B = 256;
    const int gF = (N_NODES + FL_TILE - 1) / FL_TILE;   // 1563

    hipLaunchKernelGGL(k_pre, dim3(VOCAB), dim3(H), 0, stream,
                       emb, conv_w, M, bcnt, sorted_e + N_EDGES);
    hipLaunchKernelGGL(k_binA, dim3(PART_BLOCKS), dim3(1024), 0, stream,
                       row, col, bcnt, blkstart, staging);
    hipLaunchKernelGGL(k_bscan, dim3(1), dim3(1024), 0, stream, bcnt, bbase);
    hipLaunchKernelGGL(k_binB, dim3(NBUCK), dim3(256), 0, stream, staging, blkstart,
                       bbase, x, sorted_e, degi, row_start, dinv, packed);

    // layer 0: vocabulary-factored, streams sorted_e; emits h + q(->qb, fp8)
    hipLaunchKernelGGL(k_gather0_mfma, dim3(NBUCK), dim3(B), 0, stream,
                       sorted_e, bbase, packed, M, dinv, conv_b, h, qb);

    // layers 1,2: fused gather + MFMA transform (h@W commutes with aggregation)
    hipLaunchKernelGGL(k_fused, dim3(gF), dim3(512), 0, stream,
                       sorted_e, row_start, degi, qb, dinv,
                       conv_w + (size_t)1 * H * H, conv_b + 1 * H, h, qa, 0);
    hipLaunchKernelGGL(k_fused, dim3(gF), dim3(512), 0, stream,
                       sorted_e, row_start, degi, qa, dinv,
                       conv_w + (size_t)2 * H * H, conv_b + 2 * H, h, qb, 1);

    hipLaunchKernelGGL(k_poolmlp, dim3(N_GRAPHS), dim3(256), 0, stream,
                       h, batch, w1, b1, w2, b2, w3, b3, out);

    (void)in_sizes; (void)n_in; (void)out_size; (void)ws_size;
}